// Round 5
// baseline (252.843 us; speedup 1.0000x reference)
//
#include <hip/hip_runtime.h>

// R5: attention moved to mfma_32x32x16 (2x MACs per LDS byte; LDS-pipe was the
// measured structural limit of the 16x16 design). Wave owns 32q; Q in regs as
// B-frags; S^T C-layout -> packed b64 P-writes -> natural A-frag reload.
// GEMM/cast side identical to R4 (isolate attribution).
#define DIM 512
#define NQ 2048
#define MA 2048
#define MS 256
#define QSCALE 0.06375864651f  // 512^-0.5 * log2(e)

typedef __attribute__((ext_vector_type(8))) short bf16x8;
typedef __attribute__((ext_vector_type(4))) float f32x4;
typedef __attribute__((ext_vector_type(16))) float f32x16;

__device__ __forceinline__ ushort f2b(float f) {
    uint u = __float_as_uint(f);
    u = (u + 0x7fffu + ((u >> 16) & 1u)) >> 16;
    return (ushort)u;
}

__device__ __forceinline__ void gload16(const ushort* g, ushort* l) {
    __builtin_amdgcn_global_load_lds(
        (const __attribute__((address_space(1))) void*)g,
        (__attribute__((address_space(3))) void*)l, 16, 0, 0);
}

// ---- fused cast: 6 weights + x + ac + scx -> contiguous bf16 region ----
__global__ __launch_bounds__(256) void cast_all(const float* __restrict__ w0,
                                                const float* __restrict__ w1,
                                                const float* __restrict__ w2,
                                                const float* __restrict__ w3,
                                                const float* __restrict__ w4,
                                                const float* __restrict__ w5,
                                                const float* __restrict__ x,
                                                const float* __restrict__ ac,
                                                const float* __restrict__ scx,
                                                ushort* __restrict__ dst) {
    int i = blockIdx.x * 256 + threadIdx.x;  // float4 index, 2621440 total
    const float* s;
    int o;
    if (i < 393216) {
        int w = i >> 16;
        s = w < 3 ? (w == 0 ? w0 : (w == 1 ? w1 : w2))
                  : (w == 3 ? w3 : (w == 4 ? w4 : w5));
        o = i & 65535;
    } else if (i < 1441792) { s = x;   o = i - 393216; }
    else if (i < 2490368)   { s = ac;  o = i - 1441792; }
    else                    { s = scx; o = i - 2490368; }
    float4 v = ((const float4*)s)[o];
    ushort4 u;
    u.x = f2b(v.x); u.y = f2b(v.y); u.z = f2b(v.z); u.w = f2b(v.w);
    ((ushort4*)dst)[i] = u;
}

// ---- fused GEMM: C = A @ B^T + bias, 128x128 tile, K=512, descriptor decode ----
struct GD {
    const ushort* A; const ushort* B; const float* bias; void* out;
    long sB, sO;
    int N, bx, by, blk0, biasrow, scaleq, outf32, pad;
};

__global__ __launch_bounds__(256) void gemm_fused(GD d0, GD d1, GD d2, GD d3, GD d4) {
    __shared__ ushort At[128 * 32];
    __shared__ ushort Bt[128 * 32];
    GD d = d0;
    int bid = blockIdx.x;
    if (bid >= d1.blk0) d = d1;
    if (bid >= d2.blk0) d = d2;
    if (bid >= d3.blk0) d = d3;
    if (bid >= d4.blk0) d = d4;
    int local = bid - d.blk0;
    int x = local % d.bx;
    int rem = local / d.bx;
    int y = rem % d.by;
    int z = rem / d.by;

    int t = threadIdx.x;
    int wv = t >> 6, ln = t & 63, l = ln & 15, g = ln >> 4;
    int wrow = wv & 1, wcol = wv >> 1;
    int row0 = x * 128, col0 = y * 128;
    int srow = t >> 2;
    int slot = (t & 3) * 8;
    int sko = ((t ^ srow) & 3) * 8;        // XOR-swizzled global k-chunk
    int kc8 = ((g ^ (l & 3)) & 3) * 8;     // reader un-swizzle
    const ushort* Ab = d.A;
    const ushort* Bb = d.B + (size_t)z * d.sB;
    int N = d.N;

    f32x4 acc[4][4];
#pragma unroll
    for (int i = 0; i < 4; i++)
#pragma unroll
        for (int j = 0; j < 4; j++) acc[i][j] = (f32x4){0, 0, 0, 0};

    for (int k0 = 0; k0 < 512; k0 += 32) {
        __syncthreads();
#pragma unroll
        for (int c = 0; c < 2; c++) {
            gload16(Ab + (size_t)(row0 + srow + 64 * c) * 512 + k0 + sko,
                    At + (srow + 64 * c) * 32 + slot);
            gload16(Bb + (size_t)(col0 + srow + 64 * c) * 512 + k0 + sko,
                    Bt + (srow + 64 * c) * 32 + slot);
        }
        __syncthreads();
        bf16x8 ar[4], br[4];
#pragma unroll
        for (int i = 0; i < 4; i++)
            ar[i] = *(const bf16x8*)(At + (wrow * 64 + i * 16 + l) * 32 + kc8);
#pragma unroll
        for (int j = 0; j < 4; j++)
            br[j] = *(const bf16x8*)(Bt + (wcol * 64 + j * 16 + l) * 32 + kc8);
#pragma unroll
        for (int i = 0; i < 4; i++)
#pragma unroll
            for (int j = 0; j < 4; j++)
                acc[i][j] = __builtin_amdgcn_mfma_f32_16x16x32_bf16(ar[i], br[j], acc[i][j], 0, 0, 0);
    }
#pragma unroll
    for (int i = 0; i < 4; i++) {
#pragma unroll
        for (int j = 0; j < 4; j++) {
            int row = row0 + wrow * 64 + i * 16 + g * 4;
            int col = col0 + wcol * 64 + j * 16 + l;
#pragma unroll
            for (int r = 0; r < 4; r++) {
                float bv = d.biasrow ? d.bias[row + r] : d.bias[col];
                float o = acc[i][j][r] + bv;
                if (d.scaleq) o *= QSCALE;
                if (d.outf32)
                    ((float*)d.out + (size_t)z * d.sO)[(size_t)(row + r) * N + col] = o;
                else
                    ((ushort*)d.out + (size_t)z * d.sO)[(size_t)(row + r) * N + col] = f2b(o);
            }
        }
    }
}

// ---- attention: 32x32x16 MFMA, wave owns 32 q rows, 4 waves/block ----
// S^T = K.Q^T (A=K ctx-rows, B=Q q-cols in regs). C-layout col=lane&31=q
// matches P A-frag m=lane&31=q -> packed b64 P-writes, b128 P-reads.
__device__ __forceinline__ void attn_ctx32(const ushort* __restrict__ kg,
                                           const ushort* __restrict__ vg,
                                           int M, const bf16x8 (&aq)[4],
                                           ushort* __restrict__ Kl,
                                           ushort* __restrict__ Vl,
                                           ushort* __restrict__ Pw,
                                           f32x16 (&o)[2], float& li,
                                           int l5, int hi, int sr, int sc) {
    bf16x8 k0 = *(const bf16x8*)kg;
    bf16x8 k1 = *(const bf16x8*)(kg + (size_t)32 * DIM);
    bf16x8 v0 = *(const bf16x8*)vg;
    bf16x8 v1 = *(const bf16x8*)(vg + (size_t)32 * M);
    for (int mt = 0; mt < M; mt += 64) {
        __syncthreads();
        *(bf16x8*)(Kl + sr * 72 + sc) = k0;
        *(bf16x8*)(Kl + (sr + 32) * 72 + sc) = k1;
        *(bf16x8*)(Vl + sr * 72 + sc) = v0;
        *(bf16x8*)(Vl + (sr + 32) * 72 + sc) = v1;
        __syncthreads();
        if (mt + 64 < M) {  // preload next tile behind compute
            k0 = *(const bf16x8*)(kg + (size_t)(mt + 64) * DIM);
            k1 = *(const bf16x8*)(kg + (size_t)(mt + 96) * DIM);
            v0 = *(const bf16x8*)(vg + (mt + 64));
            v1 = *(const bf16x8*)(vg + (size_t)32 * M + (mt + 64));
        }
#pragma unroll
        for (int c = 0; c < 2; c++) {
            f32x16 s;
#pragma unroll
            for (int i = 0; i < 16; i++) s[i] = 0.f;
#pragma unroll
            for (int kd = 0; kd < 4; kd++) {
                bf16x8 kf = *(const bf16x8*)(Kl + (32 * c + l5) * 72 + kd * 16 + hi * 8);
                s = __builtin_amdgcn_mfma_f32_32x32x16_bf16(kf, aq[kd], s, 0, 0, 0);
            }
            // lane holds q=l5, ctx rows (m&3)+8*(m>>2)+4*hi+32c per reg-quad;
            // quad = 4 consecutive ctx -> one b64 write
#pragma unroll
            for (int m = 0; m < 4; m++) {
                float p0 = exp2f(s[4 * m + 0]);
                float p1 = exp2f(s[4 * m + 1]);
                float p2 = exp2f(s[4 * m + 2]);
                float p3 = exp2f(s[4 * m + 3]);
                li += (p0 + p1) + (p2 + p3);
                uint2 pw;
                pw.x = ((__float_as_uint(p0) + 0x8000u) >> 16) |
                       ((__float_as_uint(p1) + 0x8000u) & 0xffff0000u);
                pw.y = ((__float_as_uint(p2) + 0x8000u) >> 16) |
                       ((__float_as_uint(p3) + 0x8000u) & 0xffff0000u);
                *(uint2*)(Pw + l5 * 72 + 32 * c + 8 * m + 4 * hi) = pw;
            }
        }
        // PV: A = P[q][ctx] (natural b128), B = V^T[d][ctx]
        bf16x8 pf[4];
#pragma unroll
        for (int kc = 0; kc < 4; kc++)
            pf[kc] = *(const bf16x8*)(Pw + l5 * 72 + kc * 16 + hi * 8);
#pragma unroll
        for (int dn = 0; dn < 2; dn++)
#pragma unroll
            for (int kc = 0; kc < 4; kc++) {
                bf16x8 vf = *(const bf16x8*)(Vl + (32 * dn + l5) * 72 + kc * 16 + hi * 8);
                o[dn] = __builtin_amdgcn_mfma_f32_32x32x16_bf16(pf[kc], vf, o[dn], 0, 0, 0);
            }
    }
}

__global__ __launch_bounds__(256) void attn_kernel(const ushort* __restrict__ q,
                                                   const ushort* __restrict__ Ka,
                                                   const ushort* __restrict__ VTa,
                                                   const ushort* __restrict__ Ks,
                                                   const ushort* __restrict__ VTs,
                                                   ushort* __restrict__ y) {
    __shared__ ushort Kl[64 * 72];
    __shared__ ushort Vl[64 * 72];
    __shared__ ushort Pl[4 * 32 * 72];
    int t = threadIdx.x;
    int wv = t >> 6, ln = t & 63, l5 = ln & 31, hi = ln >> 5;
    int h = blockIdx.y, bi = blockIdx.z;
    int q0 = blockIdx.x * 128 + wv * 32;
    bf16x8 aq[4];
    const ushort* qp = q + (size_t)(bi * NQ + q0 + l5) * DIM + h * 64 + hi * 8;
#pragma unroll
    for (int kd = 0; kd < 4; kd++) aq[kd] = *(const bf16x8*)(qp + kd * 16);
    int sr = t >> 3, sc = (t & 7) * 8;
    ushort* Pw = Pl + wv * 32 * 72;

    f32x16 o[2];
#pragma unroll
    for (int dn = 0; dn < 2; dn++)
#pragma unroll
        for (int i = 0; i < 16; i++) o[dn][i] = 0.f;
    float li = 0.f;

    // singer (short) first
    attn_ctx32(Ks + (size_t)bi * MS * DIM + (size_t)sr * DIM + h * 64 + sc,
               VTs + (size_t)bi * DIM * MS + (size_t)(h * 64 + sr) * MS + sc,
               MS, aq, Kl, Vl, Pw, o, li, l5, hi, sr, sc);
    li += __shfl_xor(li, 32);
    float inv[16];
#pragma unroll
    for (int rg = 0; rg < 16; rg++)
        inv[rg] = 1.f / __shfl(li, (rg & 3) + 8 * (rg >> 2) + 4 * hi);
    float yv[2][16];
#pragma unroll
    for (int dn = 0; dn < 2; dn++)
#pragma unroll
        for (int rg = 0; rg < 16; rg++) yv[dn][rg] = o[dn][rg] * inv[rg];

#pragma unroll
    for (int dn = 0; dn < 2; dn++)
#pragma unroll
        for (int i = 0; i < 16; i++) o[dn][i] = 0.f;
    li = 0.f;
    attn_ctx32(Ka + (size_t)bi * MA * DIM + (size_t)sr * DIM + h * 64 + sc,
               VTa + (size_t)bi * DIM * MA + (size_t)(h * 64 + sr) * MA + sc,
               MA, aq, Kl, Vl, Pw, o, li, l5, hi, sr, sc);
    li += __shfl_xor(li, 32);
#pragma unroll
    for (int rg = 0; rg < 16; rg++)
        inv[rg] = 1.f / __shfl(li, (rg & 3) + 8 * (rg >> 2) + 4 * hi);

    // O: lane holds d = 32*dn + l5, q = (rg&3)+8*(rg>>2)+4*hi
#pragma unroll
    for (int dn = 0; dn < 2; dn++)
#pragma unroll
        for (int rg = 0; rg < 16; rg++) {
            int qr = (rg & 3) + 8 * (rg >> 2) + 4 * hi;
            float ov = yv[dn][rg] + o[dn][rg] * inv[rg];
            y[(size_t)(bi * NQ + q0 + qr) * DIM + h * 64 + 32 * dn + l5] = f2b(ov);
        }
}

extern "C" void kernel_launch(void* const* d_in, const int* in_sizes, int n_in,
                              void* d_out, int out_size, void* d_ws, size_t ws_size,
                              hipStream_t stream) {
    const float* x   = (const float*)d_in[0];
    const float* ac  = (const float*)d_in[1];
    const float* scx = (const float*)d_in[2];
    const float* Wq  = (const float*)d_in[3];
    const float* bq  = (const float*)d_in[4];
    const float* Wka = (const float*)d_in[5];
    const float* bka = (const float*)d_in[6];
    const float* Wva = (const float*)d_in[7];
    const float* bva = (const float*)d_in[8];
    const float* Wks = (const float*)d_in[9];
    const float* bks = (const float*)d_in[10];
    const float* Wvs = (const float*)d_in[11];
    const float* bvs = (const float*)d_in[12];
    const float* Wp  = (const float*)d_in[13];
    const float* bp  = (const float*)d_in[14];

    ushort* wb   = (ushort*)d_ws;         // contiguous cast dst:
    ushort* wqb  = wb;                    // [6 weights][xb][acb][scxb]
    ushort* wkab = wb + 262144;
    ushort* wvab = wb + 2 * 262144;
    ushort* wksb = wb + 3 * 262144;
    ushort* wvsb = wb + 4 * 262144;
    ushort* wpb  = wb + 5 * 262144;
    ushort* xb   = wb + 6 * 262144;       // [8192][512]
    ushort* acb  = xb + 4194304;          // [8192][512]
    ushort* scxb = acb + 4194304;         // [1024][512]
    ushort* qb   = scxb + 524288;         // [8192][512] prescaled q
    ushort* kab  = qb + 4194304;          // [8192][512]
    ushort* vta  = kab + 4194304;         // [4][512][2048] V^T
    ushort* ksb  = vta + 4194304;         // [1024][512]
    ushort* vts  = ksb + 524288;          // [4][512][256]  V^T
    ushort* yb   = xb;                    // alias: x dead after gemm_fused

    cast_all<<<10240, 256, 0, stream>>>(Wq, Wka, Wva, Wks, Wvs, Wp, x, ac, scx, wb);

    GD gq   = {xb,   wqb,  bq,  qb,  0, 0,               512,  64, 4,  0,   0, 1, 0, 0};
    GD gka  = {acb,  wkab, bka, kab, 0, 0,               512,  64, 4,  256, 0, 0, 0, 0};
    GD gvta = {wvab, acb,  bva, vta, 2048L * 512, 512L * 2048, 2048, 4, 16, 512, 1, 0, 0, 0};
    GD gks  = {scxb, wksb, bks, ksb, 0, 0,               512,  8,  4,  768, 0, 0, 0, 0};
    GD gvts = {wvsb, scxb, bvs, vts, 256L * 512, 512L * 256,   256,  4,  2,  800, 1, 0, 0, 0};
    gemm_fused<<<832, 256, 0, stream>>>(gq, gka, gvta, gks, gvts);

    attn_kernel<<<dim3(16, 8, 4), 256, 0, stream>>>(qb, kab, vta, ksb, vts, yb);

    GD gpr = {yb, wpb, bp, d_out, 0, 0, 512, 64, 4, 0, 0, 0, 1, 0};
    GD gnv = {nullptr, nullptr, nullptr, nullptr, 0, 0, 0, 1, 1, 1 << 30, 0, 0, 0, 0};
    gemm_fused<<<256, 256, 0, stream>>>(gpr, gnv, gnv, gnv, gnv);
}